// Round 1
// baseline (2886.145 us; speedup 1.0000x reference)
//
#include <hip/hip_runtime.h>
#include <hip/hip_bf16.h>
#include <cstdint>

// ---------------------------------------------------------------------------
// SentenceEncoder: emb-gather -> LSTM(T=128,H=1024) over combined batch 512
// (question 0..255, sentence 256..511) -> max-over-time -> linear(2) -> sigmoid
//
// Gate permutation: output gate-column p = 4*j + g  (g in {i,f,g,o}), so a
// 64-wide N tile holds 16 complete (i,f,g,o) quadruples -> cell update fuses
// into the GEMM epilogue.
// ---------------------------------------------------------------------------

typedef __bf16 bf16x8 __attribute__((ext_vector_type(8)));
typedef float f32x4 __attribute__((ext_vector_type(4)));

__device__ __forceinline__ float sigm(float x) {
    return 1.0f / (1.0f + __expf(-x));
}
__device__ __forceinline__ float tanh_fast(float x) {
    x = fminf(15.0f, fmaxf(-15.0f, x));
    float e = __expf(2.0f * x);
    return (e - 1.0f) / (e + 1.0f);
}
__device__ __forceinline__ ushort f2bu(float f) {
    __hip_bfloat16 h = __float2bfloat16(f);
    return __builtin_bit_cast(unsigned short, h);
}

// ---------------------------------------------------------------------------
// Kernel 1: weight prep. WcT[p][k] bf16, p = 4*j+g permuted gate col,
// k: 0..511 = input dims (W_ih), 512..1535 = hidden dims (W_hh).
// biasc[p] = b_ih[r] + b_hh[r].
// grid (6, 4096), block 256.
// ---------------------------------------------------------------------------
__global__ void prep_weights(const float* __restrict__ Wih,
                             const float* __restrict__ Whh,
                             const float* __restrict__ bih,
                             const float* __restrict__ bhh,
                             __hip_bfloat16* __restrict__ WcT,
                             float* __restrict__ biasc) {
    int p = blockIdx.y;
    int k = blockIdx.x * blockDim.x + threadIdx.x;  // 0..1535
    int r = (p & 3) * 1024 + (p >> 2);              // original row: g*1024 + j
    float v = (k < 512) ? Wih[(size_t)r * 512 + k]
                        : Whh[(size_t)r * 1024 + (k - 512)];
    WcT[(size_t)p * 1536 + k] = __float2bfloat16(v);
    if (k == 0) biasc[p] = bih[r] + bhh[r];
}

// ---------------------------------------------------------------------------
// Kernel 2: embedding gather -> X bf16 [t][b'][d], b' = q:0..255, s:256..511.
// grid 65536 (= t*512+b'), block 256 (2 elems/thread via float2).
// ---------------------------------------------------------------------------
__global__ void gather_embed(const int* __restrict__ q,
                             const int* __restrict__ s,
                             const float* __restrict__ emb,
                             ushort* __restrict__ X) {
    int rb = blockIdx.x;          // t*512 + b'
    int t = rb >> 9;
    int b = rb & 511;
    int tok = (b < 256) ? q[b * 128 + t] : s[(b - 256) * 128 + t];
    const float2* src = (const float2*)(emb + (size_t)tok * 512);
    ushort2* dst = (ushort2*)(X + (size_t)rb * 512);
    float2 v = src[threadIdx.x];
    ushort2 o;
    o.x = f2bu(v.x);
    o.y = f2bu(v.y);
    dst[threadIdx.x] = o;
}

// ---------------------------------------------------------------------------
// Kernel 3: state init. c=0, hmax=-1e30, h0=0. grid 2048, block 256.
// ---------------------------------------------------------------------------
__global__ void init_state(float* __restrict__ C, float* __restrict__ HMAX,
                           ushort* __restrict__ H0) {
    int i = blockIdx.x * 256 + threadIdx.x;
    C[i] = 0.0f;
    HMAX[i] = -1e30f;
    H0[i] = 0;
}

// ---------------------------------------------------------------------------
// Kernel 4: one LSTM step for all 512 rows.
//   gates[512,4096] = [X_t | H_in] @ WcT^T   (K = 1536, bf16 MFMA)
//   then fused cell update on the 64x64 tile (16 j-quadruples).
// grid (64, 8): x = N tile (gate cols), y = M tile (batch rows). block 256.
// ---------------------------------------------------------------------------
__global__ __launch_bounds__(256, 2) void lstm_step(
    const ushort* __restrict__ X,     // [128][512][512] bf16
    const ushort* __restrict__ WcT,   // [4096][1536] bf16
    const float* __restrict__ biasc,  // [4096]
    const ushort* __restrict__ Hin,   // [512][1024] bf16
    ushort* __restrict__ Hout,        // [512][1024] bf16
    float* __restrict__ C,            // [512][1024]
    float* __restrict__ HMAX,         // [512][1024]
    int t) {
    __shared__ __align__(16) ushort As[64][72];  // batch rows x K-chunk (+8 pad)
    __shared__ __align__(16) ushort Bs[64][72];  // gate cols  x K-chunk (+8 pad)
    __shared__ float Gs[64][68];                 // gate tile fp32
    __shared__ float biasS[64];

    const int tid = threadIdx.x;
    const int m0 = blockIdx.y * 64;
    const int n0 = blockIdx.x * 64;

    if (tid < 64) biasS[tid] = biasc[n0 + tid];

    const int lane = tid & 63;
    const int w = tid >> 6;
    const int quad = lane >> 4;
    const int l16 = lane & 15;
    const int wm = (w >> 1) * 32;  // wave M offset within tile
    const int wn = (w & 1) * 32;   // wave N offset within tile

    f32x4 acc[2][2] = {};

    // staging: 64 rows x 64 bf16 each for A and B; thread handles 2 rows
    // (r1, r1+32), one 16B segment each.
    const int r1 = tid >> 3;
    const int seg = (tid & 7) * 8;  // k offset of the 8-elem segment

    for (int it = 0; it < 24; ++it) {
        const int kk = it * 64 + seg;  // uniform side of the 512 boundary
        const ushort* a1;
        const ushort* a2;
        if (kk < 512) {
            const ushort* xbase = X + (size_t)(t * 512 + m0) * 512 + kk;
            a1 = xbase + (size_t)r1 * 512;
            a2 = xbase + (size_t)(r1 + 32) * 512;
        } else {
            const ushort* hbase = Hin + (size_t)m0 * 1024 + (kk - 512);
            a1 = hbase + (size_t)r1 * 1024;
            a2 = hbase + (size_t)(r1 + 32) * 1024;
        }
        const ushort* b1 = WcT + (size_t)(n0 + r1) * 1536 + kk;
        const ushort* b2 = WcT + (size_t)(n0 + r1 + 32) * 1536 + kk;
        uint4 va1 = *(const uint4*)a1;
        uint4 va2 = *(const uint4*)a2;
        uint4 vb1 = *(const uint4*)b1;
        uint4 vb2 = *(const uint4*)b2;
        __syncthreads();  // protect LDS from previous iteration's readers
        *(uint4*)&As[r1][seg] = va1;
        *(uint4*)&As[r1 + 32][seg] = va2;
        *(uint4*)&Bs[r1][seg] = vb1;
        *(uint4*)&Bs[r1 + 32][seg] = vb2;
        __syncthreads();
#pragma unroll
        for (int kc = 0; kc < 2; ++kc) {
            bf16x8 a0 = *(const bf16x8*)&As[wm + l16][kc * 32 + quad * 8];
            bf16x8 a1f = *(const bf16x8*)&As[wm + 16 + l16][kc * 32 + quad * 8];
            bf16x8 b0 = *(const bf16x8*)&Bs[wn + l16][kc * 32 + quad * 8];
            bf16x8 b1f = *(const bf16x8*)&Bs[wn + 16 + l16][kc * 32 + quad * 8];
            acc[0][0] = __builtin_amdgcn_mfma_f32_16x16x32_bf16(a0, b0, acc[0][0], 0, 0, 0);
            acc[0][1] = __builtin_amdgcn_mfma_f32_16x16x32_bf16(a0, b1f, acc[0][1], 0, 0, 0);
            acc[1][0] = __builtin_amdgcn_mfma_f32_16x16x32_bf16(a1f, b0, acc[1][0], 0, 0, 0);
            acc[1][1] = __builtin_amdgcn_mfma_f32_16x16x32_bf16(a1f, b1f, acc[1][1], 0, 0, 0);
        }
    }
    __syncthreads();

    // spill accumulators (gate pre-activations) to LDS.
    // C/D layout: col = lane&15 (n), row = quad*4 + reg (m).
#pragma unroll
    for (int mt = 0; mt < 2; ++mt)
#pragma unroll
        for (int nt = 0; nt < 2; ++nt)
#pragma unroll
            for (int rg = 0; rg < 4; ++rg)
                Gs[wm + mt * 16 + quad * 4 + rg][wn + nt * 16 + l16] =
                    acc[mt][nt][rg];
    __syncthreads();

    // fused LSTM cell update: 64 rows x 16 j-cols; thread -> (m, 4 j's)
    const int m = tid >> 2;
    const int jb = (tid & 3) * 4;
    const size_t gbase = (size_t)(m0 + m) * 1024 + (n0 >> 2) + jb;

    f32x4 cold = *(const f32x4*)&C[gbase];
    f32x4 hm = *(const f32x4*)&HMAX[gbase];
    f32x4 cnew, hv;
#pragma unroll
    for (int u = 0; u < 4; ++u) {
        int jj = jb + u;
        float gi = Gs[m][4 * jj + 0] + biasS[4 * jj + 0];
        float gf = Gs[m][4 * jj + 1] + biasS[4 * jj + 1];
        float gg = Gs[m][4 * jj + 2] + biasS[4 * jj + 2];
        float go = Gs[m][4 * jj + 3] + biasS[4 * jj + 3];
        float iv = sigm(gi);
        float fv = sigm(gf);
        float gv = tanh_fast(gg);
        float ov = sigm(go);
        float cn = fv * cold[u] + iv * gv;
        float h = ov * tanh_fast(cn);
        cnew[u] = cn;
        hv[u] = h;
        hm[u] = fmaxf(hm[u], h);
    }
    *(f32x4*)&C[gbase] = cnew;
    *(f32x4*)&HMAX[gbase] = hm;
    ushort4 hb;
    hb.x = f2bu(hv[0]);
    hb.y = f2bu(hv[1]);
    hb.z = f2bu(hv[2]);
    hb.w = f2bu(hv[3]);
    *(ushort4*)&Hout[gbase] = hb;
}

// ---------------------------------------------------------------------------
// Kernel 5: out[b][cls] = sigmoid(b_last[cls] + hq . Wl[cls][0:1024]
//                                             + hs . Wl[cls][1024:2048])
// grid 256 (one per b), block 256.
// ---------------------------------------------------------------------------
__global__ void final_out(const float* __restrict__ HMAX,
                          const float* __restrict__ Wl,
                          const float* __restrict__ bl,
                          float* __restrict__ out) {
    int b = blockIdx.x;
    int tid = threadIdx.x;
    float s0 = 0.0f, s1 = 0.0f;
    for (int j = tid; j < 1024; j += 256) {
        float hq = HMAX[(size_t)b * 1024 + j];
        float hs = HMAX[(size_t)(256 + b) * 1024 + j];
        s0 += hq * Wl[j] + hs * Wl[1024 + j];
        s1 += hq * Wl[2048 + j] + hs * Wl[3072 + j];
    }
    __shared__ float r0[256], r1[256];
    r0[tid] = s0;
    r1[tid] = s1;
    __syncthreads();
    for (int off = 128; off > 0; off >>= 1) {
        if (tid < off) {
            r0[tid] += r0[tid + off];
            r1[tid] += r1[tid + off];
        }
        __syncthreads();
    }
    if (tid == 0) {
        out[b * 2 + 0] = sigm(r0[0] + bl[0]);
        out[b * 2 + 1] = sigm(r1[0] + bl[1]);
    }
}

// ---------------------------------------------------------------------------
extern "C" void kernel_launch(void* const* d_in, const int* in_sizes, int n_in,
                              void* d_out, int out_size, void* d_ws,
                              size_t ws_size, hipStream_t stream) {
    const int* q = (const int*)d_in[0];
    const int* s = (const int*)d_in[1];
    const float* emb = (const float*)d_in[2];
    const float* Wih = (const float*)d_in[3];
    const float* Whh = (const float*)d_in[4];
    const float* bih = (const float*)d_in[5];
    const float* bhh = (const float*)d_in[6];
    const float* Wl = (const float*)d_in[7];
    const float* bl = (const float*)d_in[8];
    float* out = (float*)d_out;

    // workspace layout (bytes, all 16B-aligned); total 85,999,616
    char* ws = (char*)d_ws;
    __hip_bfloat16* WcT = (__hip_bfloat16*)(ws + 0);          // 12,582,912
    float* biasc = (float*)(ws + 12582912);                   //     16,384
    ushort* X = (ushort*)(ws + 12599296);                     // 67,108,864
    ushort* H0 = (ushort*)(ws + 79708160);                    //  1,048,576
    ushort* H1 = (ushort*)(ws + 80756736);                    //  1,048,576
    float* C = (float*)(ws + 81805312);                       //  2,097,152
    float* HMAX = (float*)(ws + 83902464);                    //  2,097,152

    prep_weights<<<dim3(6, 4096), 256, 0, stream>>>(Wih, Whh, bih, bhh, WcT,
                                                    biasc);
    gather_embed<<<65536, 256, 0, stream>>>(q, s, emb, X);
    init_state<<<2048, 256, 0, stream>>>(C, HMAX, H0);

    ushort* hin = H0;
    ushort* hout = H1;
    for (int t = 0; t < 128; ++t) {
        lstm_step<<<dim3(64, 8), 256, 0, stream>>>(X, (const ushort*)WcT, biasc,
                                                   hin, hout, C, HMAX, t);
        ushort* tmp = hin;
        hin = hout;
        hout = tmp;
    }
    final_out<<<256, 256, 0, stream>>>(HMAX, Wl, bl, out);
}

// Round 2
// 2496.468 us; speedup vs baseline: 1.1561x; 1.1561x over previous
//
#include <hip/hip_runtime.h>
#include <hip/hip_bf16.h>
#include <cstdint>

// ---------------------------------------------------------------------------
// SentenceEncoder: emb-gather -> Xproj = X @ W_ih^T (chunked GEMM, hoisted out
// of the recurrence) -> 128x LSTM step (K=1024 h-projection only, fused cell
// update) -> max-over-time -> linear(2) -> sigmoid.
//
// Gate permutation p = 4*j + g so each N tile holds complete (i,f,g,o) quads.
// LDS layouts use an XOR swizzle (col-unit ^ (row&15)) compatible with
// global_load_lds (no padding allowed): staging writes are DMA-sequential,
// frag ds_read_b128 hit every bank exactly 8x (conflict-free).
// ---------------------------------------------------------------------------

typedef __bf16 bf16x8 __attribute__((ext_vector_type(8)));
typedef float f32x4 __attribute__((ext_vector_type(4)));

__device__ __forceinline__ float sigm(float x) {
    return 1.0f / (1.0f + __expf(-x));
}
__device__ __forceinline__ float tanh_fast(float x) {
    x = fminf(15.0f, fmaxf(-15.0f, x));
    float e = __expf(2.0f * x);
    return (e - 1.0f) / (e + 1.0f);
}
__device__ __forceinline__ ushort f2bu(float f) {
    __hip_bfloat16 h = __float2bfloat16(f);
    return __builtin_bit_cast(unsigned short, h);
}
__device__ __forceinline__ float bu2f(ushort u) {
    return __uint_as_float(((unsigned)u) << 16);
}
__device__ __forceinline__ void gl_lds16(const void* g, void* l) {
    __builtin_amdgcn_global_load_lds(
        (const __attribute__((address_space(1))) unsigned int*)g,
        (__attribute__((address_space(3))) unsigned int*)l, 16, 0, 0);
}

// ---------------------------------------------------------------------------
// Kernel 1: weight prep. WcT[p][k] bf16, p = 4*j+g permuted gate col,
// k: 0..511 = input dims (W_ih), 512..1535 = hidden dims (W_hh).
// ---------------------------------------------------------------------------
__global__ void prep_weights(const float* __restrict__ Wih,
                             const float* __restrict__ Whh,
                             const float* __restrict__ bih,
                             const float* __restrict__ bhh,
                             __hip_bfloat16* __restrict__ WcT,
                             float* __restrict__ biasc) {
    int p = blockIdx.y;
    int k = blockIdx.x * blockDim.x + threadIdx.x;  // 0..1535
    int r = (p & 3) * 1024 + (p >> 2);              // original row: g*1024 + j
    float v = (k < 512) ? Wih[(size_t)r * 512 + k]
                        : Whh[(size_t)r * 1024 + (k - 512)];
    WcT[(size_t)p * 1536 + k] = __float2bfloat16(v);
    if (k == 0) biasc[p] = bih[r] + bhh[r];
}

// ---------------------------------------------------------------------------
// Kernel 2: embedding gather -> X bf16 [t][b'][512], b' = q:0..255, s:256..511.
// ---------------------------------------------------------------------------
__global__ void gather_embed(const int* __restrict__ q,
                             const int* __restrict__ s,
                             const float* __restrict__ emb,
                             ushort* __restrict__ X) {
    int rb = blockIdx.x;  // t*512 + b'
    int t = rb >> 9;
    int b = rb & 511;
    int tok = (b < 256) ? q[b * 128 + t] : s[(b - 256) * 128 + t];
    const float2* src = (const float2*)(emb + (size_t)tok * 512);
    ushort2* dst = (ushort2*)(X + (size_t)rb * 512);
    float2 v = src[threadIdx.x];
    ushort2 o;
    o.x = f2bu(v.x);
    o.y = f2bu(v.y);
    dst[threadIdx.x] = o;
}

// ---------------------------------------------------------------------------
// Kernel 3: state init. c=0, hmax=-1e30, h0=0.
// ---------------------------------------------------------------------------
__global__ void init_state(float* __restrict__ C, float* __restrict__ HMAX,
                           ushort* __restrict__ H0) {
    int i = blockIdx.x * 256 + threadIdx.x;
    C[i] = 0.0f;
    HMAX[i] = -1e30f;
    H0[i] = 0;
}

// ---------------------------------------------------------------------------
// Kernel 4: Xproj chunk GEMM. Xb[r][p] = sum_k X[row0+r][k] * WcT[p][k],
// r in [0,4096) (8 timesteps x 512 batch), p in [0,4096), K=512.
// Tiles: 128x128 per block, BK=128 (4 iters), 4 waves of 64x64 (4x4 acc).
// grid (32 nt, 32 mtile), block 256.
// ---------------------------------------------------------------------------
__global__ __launch_bounds__(256, 2) void xproj_gemm(
    const ushort* __restrict__ X,    // [65536][512] bf16
    const ushort* __restrict__ WcT,  // [4096][1536] bf16
    ushort* __restrict__ Xb,         // [4096][4096] bf16 (chunk)
    int row0) {
    __shared__ __align__(16) ushort As[128 * 128];  // 32 KB, swizzled units
    __shared__ __align__(16) ushort Bs[128 * 128];  // 32 KB

    const int tid = threadIdx.x;
    const int n0 = blockIdx.x * 128;
    const int m0 = blockIdx.y * 128;
    const int lane = tid & 63;
    const int w = tid >> 6;
    const int quad = lane >> 4;
    const int l16 = lane & 15;
    const int wm = (w >> 1) * 64;
    const int wn = (w & 1) * 64;

    f32x4 acc[4][4] = {};

    for (int it = 0; it < 4; ++it) {
        const int k0 = it * 128;
        __syncthreads();  // previous iter's frag reads done
#pragma unroll
        for (int i = 0; i < 8; ++i) {
            int u = i * 256 + tid;          // unit index (16 B units)
            int r = u >> 4;                 // tile row 0..127
            int cs = (u & 15) ^ (r & 15);   // swizzled source col-unit
            gl_lds16(X + (size_t)(row0 + m0 + r) * 512 + k0 + cs * 8,
                     (ushort*)As + (size_t)u * 8);
            gl_lds16(WcT + (size_t)(n0 + r) * 1536 + k0 + cs * 8,
                     (ushort*)Bs + (size_t)u * 8);
        }
        __syncthreads();  // vmcnt(0) drain + barrier: LDS ready
#pragma unroll
        for (int kb = 0; kb < 4; ++kb) {
            bf16x8 af[4], bfr[4];
            const int vsel = (kb << 2) | quad;
#pragma unroll
            for (int mi = 0; mi < 4; ++mi)
                af[mi] = *(const bf16x8*)(As +
                    (((wm + mi * 16 + l16) << 4) + (vsel ^ l16)) * 8);
#pragma unroll
            for (int ni = 0; ni < 4; ++ni)
                bfr[ni] = *(const bf16x8*)(Bs +
                    (((wn + ni * 16 + l16) << 4) + (vsel ^ l16)) * 8);
#pragma unroll
            for (int mi = 0; mi < 4; ++mi)
#pragma unroll
                for (int ni = 0; ni < 4; ++ni)
                    acc[mi][ni] = __builtin_amdgcn_mfma_f32_16x16x32_bf16(
                        af[mi], bfr[ni], acc[mi][ni], 0, 0, 0);
        }
    }

    // store: C/D layout col = l16 (p), row = quad*4 + rg (chunk row)
#pragma unroll
    for (int mi = 0; mi < 4; ++mi)
#pragma unroll
        for (int ni = 0; ni < 4; ++ni)
#pragma unroll
            for (int rg = 0; rg < 4; ++rg)
                Xb[(size_t)(m0 + wm + mi * 16 + quad * 4 + rg) * 4096 +
                   (n0 + wn + ni * 16 + l16)] = f2bu(acc[mi][ni][rg]);
}

// ---------------------------------------------------------------------------
// Kernel 5: one LSTM step. gates = Hin @ Whh^T (K=1024) + Xb[t&7] + bias,
// fused cell update. Block tile 64m x 128n, BK=128 (8 iters), 4 waves of
// 32x64 (2x4 acc). grid (32 nt, 8 mt) -> consecutive blocks = consecutive nt
// -> weight tiles spread round-robin across XCDs (L2-resident, 1 MB/XCD).
// ---------------------------------------------------------------------------
__global__ __launch_bounds__(256, 2) void lstm_step(
    const ushort* __restrict__ Xb,    // [4096][4096] bf16 chunk
    const ushort* __restrict__ WcT,   // [4096][1536] bf16
    const float* __restrict__ biasc,  // [4096]
    const ushort* __restrict__ Hin,   // [512][1024] bf16
    ushort* __restrict__ Hout,        // [512][1024] bf16
    float* __restrict__ C,            // [512][1024]
    float* __restrict__ HMAX,         // [512][1024]
    int t) {
    __shared__ __align__(16) ushort As[64 * 128];   // 16 KB: Hin tile
    __shared__ __align__(16) ushort Bs[128 * 128];  // 32 KB: weight tile
    __shared__ float Gs[64][132];                   // gate tile (+4 pad)
    __shared__ float biasS[128];

    const int tid = threadIdx.x;
    const int n0 = blockIdx.x * 128;  // gate-col tile
    const int m0 = blockIdx.y * 64;   // batch-row tile

    if (tid < 128) biasS[tid] = biasc[n0 + tid];

    const int lane = tid & 63;
    const int w = tid >> 6;
    const int quad = lane >> 4;
    const int l16 = lane & 15;
    const int wm = (w >> 1) * 32;
    const int wn = (w & 1) * 64;

    f32x4 acc[2][4] = {};

    for (int it = 0; it < 8; ++it) {
        const int k0 = it * 128;
        __syncthreads();
#pragma unroll
        for (int i = 0; i < 4; ++i) {  // A: 64 rows x 16 units = 1024 units
            int u = i * 256 + tid;
            int r = u >> 4;
            int cs = (u & 15) ^ (r & 15);
            gl_lds16(Hin + (size_t)(m0 + r) * 1024 + k0 + cs * 8,
                     (ushort*)As + (size_t)u * 8);
        }
#pragma unroll
        for (int i = 0; i < 8; ++i) {  // B: 128 rows x 16 units = 2048 units
            int u = i * 256 + tid;
            int r = u >> 4;
            int cs = (u & 15) ^ (r & 15);
            gl_lds16(WcT + (size_t)(n0 + r) * 1536 + 512 + k0 + cs * 8,
                     (ushort*)Bs + (size_t)u * 8);
        }
        __syncthreads();
#pragma unroll
        for (int kb = 0; kb < 4; ++kb) {
            bf16x8 af[2], bfr[4];
            const int vsel = (kb << 2) | quad;
#pragma unroll
            for (int mi = 0; mi < 2; ++mi)
                af[mi] = *(const bf16x8*)(As +
                    (((wm + mi * 16 + l16) << 4) + (vsel ^ l16)) * 8);
#pragma unroll
            for (int ni = 0; ni < 4; ++ni)
                bfr[ni] = *(const bf16x8*)(Bs +
                    (((wn + ni * 16 + l16) << 4) + (vsel ^ l16)) * 8);
#pragma unroll
            for (int mi = 0; mi < 2; ++mi)
#pragma unroll
                for (int ni = 0; ni < 4; ++ni)
                    acc[mi][ni] = __builtin_amdgcn_mfma_f32_16x16x32_bf16(
                        af[mi], bfr[ni], acc[mi][ni], 0, 0, 0);
        }
    }

    // gate tile -> LDS (C/D layout: col=l16, row=quad*4+rg)
#pragma unroll
    for (int mi = 0; mi < 2; ++mi)
#pragma unroll
        for (int ni = 0; ni < 4; ++ni)
#pragma unroll
            for (int rg = 0; rg < 4; ++rg)
                Gs[wm + mi * 16 + quad * 4 + rg][wn + ni * 16 + l16] =
                    acc[mi][ni][rg];
    __syncthreads();

    // fused cell update: thread -> (row m, 8 j-quads)
    const int m = tid >> 2;
    const int c4 = tid & 3;
    const int col0 = c4 * 32;  // local p base (8 quads)
    const size_t hrow = (size_t)(m0 + m) * 1024;
    const int j0 = (n0 >> 2) + c4 * 8;
    const ushort* xp =
        Xb + (size_t)((t & 7) * 512 + m0 + m) * 4096 + n0 + col0;

    f32x4 cold0 = *(const f32x4*)&C[hrow + j0];
    f32x4 cold1 = *(const f32x4*)&C[hrow + j0 + 4];
    f32x4 hm0 = *(const f32x4*)&HMAX[hrow + j0];
    f32x4 hm1 = *(const f32x4*)&HMAX[hrow + j0 + 4];
    f32x4 cn0, cn1;
    ushort4 hb0, hb1;
#pragma unroll
    for (int u = 0; u < 8; ++u) {
        int cb = col0 + 4 * u;
        float gi = Gs[m][cb + 0] + bu2f(xp[4 * u + 0]) + biasS[cb + 0];
        float gf = Gs[m][cb + 1] + bu2f(xp[4 * u + 1]) + biasS[cb + 1];
        float gg = Gs[m][cb + 2] + bu2f(xp[4 * u + 2]) + biasS[cb + 2];
        float go = Gs[m][cb + 3] + bu2f(xp[4 * u + 3]) + biasS[cb + 3];
        float iv = sigm(gi);
        float fv = sigm(gf);
        float gv = tanh_fast(gg);
        float ov = sigm(go);
        float cold = (u < 4) ? cold0[u & 3] : cold1[u & 3];
        float cn = fv * cold + iv * gv;
        float h = ov * tanh_fast(cn);
        ushort hbits = f2bu(h);
        if (u < 4) {
            cn0[u & 3] = cn;
            hm0[u & 3] = fmaxf(hm0[u & 3], h);
            ((ushort*)&hb0)[u & 3] = hbits;
        } else {
            cn1[u & 3] = cn;
            hm1[u & 3] = fmaxf(hm1[u & 3], h);
            ((ushort*)&hb1)[u & 3] = hbits;
        }
    }
    *(f32x4*)&C[hrow + j0] = cn0;
    *(f32x4*)&C[hrow + j0 + 4] = cn1;
    *(f32x4*)&HMAX[hrow + j0] = hm0;
    *(f32x4*)&HMAX[hrow + j0 + 4] = hm1;
    *(ushort4*)&Hout[hrow + j0] = hb0;
    *(ushort4*)&Hout[hrow + j0 + 4] = hb1;
}

// ---------------------------------------------------------------------------
// Kernel 6: final linear + sigmoid.
// ---------------------------------------------------------------------------
__global__ void final_out(const float* __restrict__ HMAX,
                          const float* __restrict__ Wl,
                          const float* __restrict__ bl,
                          float* __restrict__ out) {
    int b = blockIdx.x;
    int tid = threadIdx.x;
    float s0 = 0.0f, s1 = 0.0f;
    for (int j = tid; j < 1024; j += 256) {
        float hq = HMAX[(size_t)b * 1024 + j];
        float hs = HMAX[(size_t)(256 + b) * 1024 + j];
        s0 += hq * Wl[j] + hs * Wl[1024 + j];
        s1 += hq * Wl[2048 + j] + hs * Wl[3072 + j];
    }
    __shared__ float r0[256], r1[256];
    r0[tid] = s0;
    r1[tid] = s1;
    __syncthreads();
    for (int off = 128; off > 0; off >>= 1) {
        if (tid < off) {
            r0[tid] += r0[tid + off];
            r1[tid] += r1[tid + off];
        }
        __syncthreads();
    }
    if (tid == 0) {
        out[b * 2 + 0] = sigm(r0[0] + bl[0]);
        out[b * 2 + 1] = sigm(r1[0] + bl[1]);
    }
}

// ---------------------------------------------------------------------------
extern "C" void kernel_launch(void* const* d_in, const int* in_sizes, int n_in,
                              void* d_out, int out_size, void* d_ws,
                              size_t ws_size, hipStream_t stream) {
    const int* q = (const int*)d_in[0];
    const int* s = (const int*)d_in[1];
    const float* emb = (const float*)d_in[2];
    const float* Wih = (const float*)d_in[3];
    const float* Whh = (const float*)d_in[4];
    const float* bih = (const float*)d_in[5];
    const float* bhh = (const float*)d_in[6];
    const float* Wl = (const float*)d_in[7];
    const float* bl = (const float*)d_in[8];
    float* out = (float*)d_out;

    // workspace layout (bytes, 16B-aligned); total 119,554,048
    char* ws = (char*)d_ws;
    __hip_bfloat16* WcT = (__hip_bfloat16*)(ws + 0);  // 12,582,912
    float* biasc = (float*)(ws + 12582912);           //     16,384
    ushort* X = (ushort*)(ws + 12599296);             // 67,108,864
    ushort* Xb = (ushort*)(ws + 79708160);            // 33,554,432
    ushort* H0 = (ushort*)(ws + 113262592);           //  1,048,576
    ushort* H1 = (ushort*)(ws + 114311168);           //  1,048,576
    float* C = (float*)(ws + 115359744);              //  2,097,152
    float* HMAX = (float*)(ws + 117456896);           //  2,097,152

    prep_weights<<<dim3(6, 4096), 256, 0, stream>>>(Wih, Whh, bih, bhh, WcT,
                                                    biasc);
    gather_embed<<<65536, 256, 0, stream>>>(q, s, emb, X);
    init_state<<<2048, 256, 0, stream>>>(C, HMAX, H0);

    ushort* hin = H0;
    ushort* hout = H1;
    for (int c = 0; c < 16; ++c) {
        xproj_gemm<<<dim3(32, 32), 256, 0, stream>>>(X, (const ushort*)WcT, Xb,
                                                     c * 4096);
        for (int tt = 0; tt < 8; ++tt) {
            int t = c * 8 + tt;
            lstm_step<<<dim3(32, 8), 256, 0, stream>>>(
                Xb, (const ushort*)WcT, biasc, hin, hout, C, HMAX, t);
            ushort* tmp = hin;
            hin = hout;
            hout = tmp;
        }
    }
    final_out<<<256, 256, 0, stream>>>(HMAX, Wl, bl, out);
}